// Round 12
// baseline (26.849 us; speedup 1.0000x reference)
//
#include <hip/hip_runtime.h>

typedef __attribute__((ext_vector_type(8)))  short    short8;   // 8 bf16 (K=32 A/B frag)
typedef __attribute__((ext_vector_type(4)))  short    s16x4;    // 4 bf16 (K=16 A/B frag)
typedef __attribute__((ext_vector_type(4)))  float    f32x4;    // 16x16 C/D frag
typedef __attribute__((ext_vector_type(4)))  unsigned uint4_;
typedef __attribute__((ext_vector_type(2)))  unsigned uint2_;

#define HW     16000
#define WWID   200
#define NPARAM 8513
// raw param offsets: w0[64][66] @0, w1[64][64] @4224, w2 @8320, b0 @8384, b1 @8448, b2 @8512
// packed ws per instance (dwords, stride 6144 = 24KB):
//   w0 K=32 A-frags [0,3072): 12 frags (ch*4+kb) x 256 dw; lane*4+d
//   w1 K=16 A-frags [3072,5120): 16 frags (kb*4+ks) x 128 dw; lane*2+d
//   b1 f32 @5120(64), w2 f32 @5184(64), b2 @5248
#define PACK_STRIDE 6144

__device__ __forceinline__ unsigned pkbf2(float a, float b) {   // 1 VALU op (RNE)
    unsigned r;
    asm("v_cvt_pk_bf16_f32 %0, %1, %2" : "=v"(r) : "v"(a), "v"(b));
    return r;
}
__device__ __forceinline__ short8 mk8(unsigned a, unsigned b, unsigned c, unsigned d) {
    uint4_ u; u.x = a; u.y = b; u.z = c; u.w = d;
    return __builtin_bit_cast(short8, u);
}
__device__ __forceinline__ s16x4 mk4(unsigned a, unsigned b) {
    uint2_ u; u.x = a; u.y = b;
    return __builtin_bit_cast(s16x4, u);
}
// K=16 bf16 MFMA via inline asm; leading s_nop 2 covers the VALU-write ->
// MFMA-read wait states the compiler can't insert through asm (R10 lesson).
__device__ __forceinline__ void mfma16(f32x4& acc, s16x4 a, s16x4 b) {
    asm("s_nop 2\n\tv_mfma_f32_16x16x16_bf16 %0, %1, %2, %0"
        : "+v"(acc) : "v"(a), "v"(b));
}

// L0 K-channel map: 0..63 -> x (w0 col c+2); 64 -> lx (col 0); 65 -> ly (col 1);
// 66 -> 1*b0; 67..95 -> 0
__device__ __forceinline__ float w0val(const float* pm, int k, int c) {
    if (c < 64)  return pm[k * 66 + c + 2];
    if (c == 64) return pm[k * 66 + 0];
    if (c == 65) return pm[k * 66 + 1];
    if (c == 66) return pm[8384 + k];
    return 0.0f;
}

// grid (M, 2) x 256 thr. y=0: w0 frags + smalls (R4-verified layout); y=1: w1 K=16 frags.
__global__ __launch_bounds__(256) void pack_weights(
    const float* __restrict__ params, unsigned* __restrict__ wp)
{
    const int m   = blockIdx.x;
    const int tid = threadIdx.x;
    const float* pm = params + (size_t)m * NPARAM;
    unsigned* dst = wp + (size_t)m * PACK_STRIDE;

    if (blockIdx.y == 0) {
        const int l  = tid >> 2;
        const int i0 = (tid & 3) * 2;
        #pragma unroll
        for (int frag = 0; frag < 12; ++frag) {        // w0, K=96 (ch*4+kb)
            int ch = frag >> 2, kb = frag & 3;
            int k = kb * 16 + (l & 15);
            int c = ch * 32 + (l >> 4) * 8 + i0;
            dst[frag * 256 + tid] = pkbf2(w0val(pm, k, c), w0val(pm, k, c + 1));
        }
        float* fd = (float*)dst;
        if (tid < 64) {
            fd[5120 + tid] = pm[8448 + tid];           // b1
            fd[5184 + tid] = pm[8320 + tid];           // w2
        }
        if (tid == 0) fd[5248] = pm[8512];             // b2
    } else {
        #pragma unroll
        for (int i = tid; i < 2048; i += 256) {        // w1 K=16 A-frags
            int f = i >> 7, r = i & 127;
            int l = r >> 1, d = i & 1;
            int kb = f >> 2, ks = f & 3;
            int row = kb * 16 + (l & 15);
            int col = ks * 16 + (l >> 4) * 4 + d * 2;
            const float* s = pm + 4224 + row * 64 + col;
            dst[3072 + i] = pkbf2(s[0], s[1]);
        }
    }
}

// block = 512 thr (8 waves); wave wid owns FULL instance m = n*num_ins+wid.
// R11 loop unchanged: relu(acc0[ks]) packed to bf16 IS L1's B operand (layout
// identity) -> h0 never leaves registers; no in-loop barriers/LDS.
// Weights now loaded COALESCED from the packed image (L2-resident).
__global__ __launch_bounds__(512, 3) void condlane_reg(
    const float* __restrict__ x,        // [N, 64, HW]
    const unsigned* __restrict__ wp,    // packed weights
    float* __restrict__ out,            // [M, HW]
    int num_ins)
{
    extern __shared__ char lds_[];
    char* xt = lds_;                    // 65536 B
    const int tid  = threadIdx.x;
    const int lane = tid & 63;
    const int wid  = tid >> 6;
    const int n    = blockIdx.y;
    const int pxg0 = blockIdx.x * 256;
    const int g    = (lane >> 4) & 3;
    const int px16 = lane & 15;

    // ---- stage x tile: [256 px][128 ch] bf16, swizzle byte ^= (p&15)<<4 ----
    {
        const int p   = tid & 255;
        const int sel = tid >> 8;       // 0..1, 32 fp32 channels each
        const int pc  = min(pxg0 + p, HW - 1);
        const float* xp = x + (size_t)n * 64 * HW + pc;
        #pragma unroll
        for (int it = 0; it < 4; ++it) {
            int c0 = sel * 32 + it * 8;
            uint4_ d;
            d.x = pkbf2(xp[(size_t)(c0 + 0) * HW], xp[(size_t)(c0 + 1) * HW]);
            d.y = pkbf2(xp[(size_t)(c0 + 2) * HW], xp[(size_t)(c0 + 3) * HW]);
            d.z = pkbf2(xp[(size_t)(c0 + 4) * HW], xp[(size_t)(c0 + 5) * HW]);
            d.w = pkbf2(xp[(size_t)(c0 + 6) * HW], xp[(size_t)(c0 + 7) * HW]);
            *(uint4_*)(xt + ((p * 256 + c0 * 2) ^ ((p & 15) << 4))) = d;
        }
        // const K-channels 64..95 = {lx, ly, 1, 0 ...}
        const int pg = pxg0 + p;        // values for pg>=HW never consumed
        float lx = (float)(pg % WWID) * (1.0f / WWID);
        float ly = (float)(pg / WWID) * (1.0f / WWID);   // source bug: also /W
        uint4_ z;  z.x = 0; z.y = 0; z.z = 0; z.w = 0;
        uint4_ cv; cv.x = pkbf2(lx, ly); cv.y = pkbf2(1.f, 0.f); cv.z = 0; cv.w = 0;
        int ba = (p * 256 + 128 + sel * 32) ^ ((p & 15) << 4);
        int bb = (p * 256 + 144 + sel * 32) ^ ((p & 15) << 4);
        *(uint4_*)(xt + ba) = (sel == 0) ? cv : z;
        *(uint4_*)(xt + bb) = z;
    }

    // ---- wave-resident weights: coalesced loads from packed image ----
    const int m = n * num_ins + wid;    // 8 waves == num_ins
    const unsigned* wm = wp + (size_t)m * PACK_STRIDE;

    short8 w0f[3][4];
    s16x4  w1f4[4][4];
    #pragma unroll
    for (int ch = 0; ch < 3; ++ch)
        #pragma unroll
        for (int kb = 0; kb < 4; ++kb)
            w0f[ch][kb] = *(const short8*)(wm + (ch * 4 + kb) * 256 + lane * 4);
    #pragma unroll
    for (int kb = 0; kb < 4; ++kb)
        #pragma unroll
        for (int ks = 0; ks < 4; ++ks)
            w1f4[kb][ks] = *(const s16x4*)(wm + 3072 + (kb * 4 + ks) * 128 + lane * 2);
    const float* fm = (const float*)wm;
    f32x4 bias1[4], w2v[4];
    #pragma unroll
    for (int kb = 0; kb < 4; ++kb) {
        bias1[kb] = *(const f32x4*)(fm + 5120 + kb * 16 + g * 4);
        w2v[kb]   = *(const f32x4*)(fm + 5184 + kb * 16 + g * 4);
    }
    const float b2 = fm[5248] - 2.19f;

    __syncthreads();                    // xt ready — the only barrier

    const int swz = px16 << 4;
    const int nsl = min(16, (HW - pxg0) >> 4);

    for (int s = 0; s < 16; ++s) {
        const int pxl = s * 16 + px16;
        short8 xf[3];
        #pragma unroll
        for (int ch = 0; ch < 3; ++ch)
            xf[ch] = *(const short8*)(xt + ((pxl * 256 + ch * 64 + g * 16) ^ swz));
        // layer 0: 12 MFMA (K=96), acc = 0 (loc+bias folded)
        f32x4 acc0[4];
        #pragma unroll
        for (int kb = 0; kb < 4; ++kb)
            #pragma unroll
            for (int j = 0; j < 4; ++j) acc0[kb][j] = 0.f;
        #pragma unroll
        for (int ch = 0; ch < 3; ++ch)
            #pragma unroll
            for (int kb = 0; kb < 4; ++kb)
                acc0[kb] = __builtin_amdgcn_mfma_f32_16x16x32_bf16(w0f[ch][kb], xf[ch], acc0[kb], 0, 0, 0);
        // relu -> bf16 in registers: acc0[ks] becomes L1's B-frag for chunk ks
        s16x4 hf[4];
        #pragma unroll
        for (int ks = 0; ks < 4; ++ks)
            hf[ks] = mk4(pkbf2(fmaxf(acc0[ks][0], 0.f), fmaxf(acc0[ks][1], 0.f)),
                         pkbf2(fmaxf(acc0[ks][2], 0.f), fmaxf(acc0[ks][3], 0.f)));
        // layer 1: 16 x K=16 MFMA (asm, hazard-protected)
        f32x4 acc1[4];
        #pragma unroll
        for (int kb = 0; kb < 4; ++kb) acc1[kb] = bias1[kb];
        #pragma unroll
        for (int ks = 0; ks < 4; ++ks)
            #pragma unroll
            for (int kb = 0; kb < 4; ++kb)
                mfma16(acc1[kb], w1f4[kb][ks], hf[ks]);
        // exit hazard: MFMA write -> VALU read (nops tied to accs for ordering)
        asm("s_nop 7\n\ts_nop 7"
            : "+v"(acc1[0]), "+v"(acc1[1]), "+v"(acc1[2]), "+v"(acc1[3]));
        // layer 2: 64->1 fp32 VALU + cross-group reduce
        float v = 0.f;
        #pragma unroll
        for (int kb = 0; kb < 4; ++kb)
            #pragma unroll
            for (int r = 0; r < 4; ++r)
                v += w2v[kb][r] * fmaxf(acc1[kb][r], 0.f);
        v += __shfl_xor(v, 16);
        v += __shfl_xor(v, 32);
        if (lane < 16 && s < nsl)
            out[(size_t)m * HW + pxg0 + s * 16 + lane] = v + b2;
    }
}

extern "C" void kernel_launch(void* const* d_in, const int* in_sizes, int n_in,
                              void* d_out, int out_size, void* d_ws, size_t ws_size,
                              hipStream_t stream) {
    const float* x      = (const float*)d_in[0];
    const float* params = (const float*)d_in[1];
    float* out          = (float*)d_out;

    const int N = in_sizes[0] / (64 * HW);   // 4
    const int M = in_sizes[1] / NPARAM;      // 32
    const int num_ins = M / N;               // 8

    pack_weights<<<dim3(M, 2), 256, 0, stream>>>(params, (unsigned*)d_ws);

    dim3 grid((HW + 255) / 256, N);          // 63 x 4 = 252 blocks
    condlane_reg<<<grid, 512, 65536, stream>>>(x, (const unsigned*)d_ws, out, num_ins);
}